// Round 17
// baseline (94.655 us; speedup 1.0000x reference)
//
#include <hip/hip_runtime.h>
#include <stdint.h>

typedef __attribute__((ext_vector_type(8))) short short8;
typedef __attribute__((ext_vector_type(4))) float f32x4;
typedef __attribute__((ext_vector_type(16))) float f32x16;
typedef __attribute__((ext_vector_type(4))) unsigned int u32x4;
typedef unsigned short u16;
typedef unsigned int u32;

#define NBATCH 8
#define SLEN 1024
#define CDIM 512
#define NHEADS 8
#define HDIM 64
#define MROWS (NBATCH*SLEN)
#define NQKV (NHEADS*3*HDIM)   // 1536
// q-scale with folded log2e: QK_SCALE^2 * log2(e) = 0.125 * 1.4426950408889634
#define Q_SCALE_L2E 0.18033688011111793f
#define DEFER_THR 11.541560327111707f   // 8 * log2(e)
#define NPREP (8*(NQKV/64) + 8*(CDIM/64))   // 320 transpose blocks

__device__ inline u16 f2bf(float f){
  union{float f; uint32_t i;} v; v.f=f;
  uint32_t r = v.i + 0x7fffu + ((v.i>>16)&1u);
  return (u16)(r>>16);
}

__device__ inline u32 pk2(float a, float b){
  u32 r;
  asm("v_cvt_pk_bf16_f32 %0, %1, %2" : "=v"(r) : "v"(a), "v"(b));
  return r;
}

// raw 2^x (v_exp_f32)
__device__ inline float exp2r(float x){
  float r;
  asm("v_exp_f32 %0, %1" : "=v"(r) : "v"(x));
  return r;
}

__device__ __forceinline__ void gld16(const u16* g, u16* l){
  __builtin_amdgcn_global_load_lds(
    (const __attribute__((address_space(1))) void*)g,
    (__attribute__((address_space(3))) void*)l, 16, 0, 0);
}

// ---------------- fused pre-pass: weight transposes + groupnorm, ONE dispatch ----
// blocks [0, NPREP): LDS-tiled transpose fp32[K=512][N] -> bf16[N][512] (512 thr)
// blocks [NPREP, NPREP+256): groupnorm stats+normalize per (b,g)
__device__ __forceinline__ void prep_body(const float* __restrict__ w, u16* __restrict__ wt,
                                          int N, int blk, int t){
  int tk = blk / (N/64), tn = blk % (N/64);
  int k0 = tk*64, n0 = tn*64;
  __shared__ u16 lt[64][72];
  int row = t >> 3, slot = t & 7;          // 64 rows x 8 slots of 8 elems
  const float* src = w + (size_t)(k0+row)*N + n0 + slot*8;
  #pragma unroll
  for (int j=0;j<8;++j)
    lt[row][slot*8+j] = f2bf(src[j]);
  __syncthreads();
  u16 tmp[8];
  #pragma unroll
  for (int j=0;j<8;++j) tmp[j] = lt[slot*8+j][row];
  *(u32x4*)(wt + (size_t)(n0+row)*512 + k0 + slot*8) = *(u32x4*)tmp;
}

__global__ __launch_bounds__(512) void pre_fused(
    const float* __restrict__ wqkv, const float* __restrict__ wout,
    u16* __restrict__ wqkv_t, u16* __restrict__ wout_t,
    const float* __restrict__ x, const float* __restrict__ scale,
    const float* __restrict__ bias, u16* __restrict__ xn){
  int blk = blockIdx.x, t = threadIdx.x;
  if (blk < NPREP){
    if (blk < 8*(NQKV/64)) prep_body(wqkv, wqkv_t, NQKV, blk, t);
    else                   prep_body(wout, wout_t, CDIM, blk - 8*(NQKV/64), t);
    return;
  }
  int bid = blk - NPREP;           // b*32+g
  int b = bid >> 5, g = bid & 31;
  const float* base = x + (size_t)b*SLEN*CDIM + g*16;
  u16* obase = xn + (size_t)b*SLEN*CDIM + g*16;
  float s1=0.f, s2=0.f;
  for (int s = t; s < SLEN; s += 512){
    const float4* p = (const float4*)(base + (size_t)s*CDIM);
    #pragma unroll
    for (int j=0;j<4;++j){
      float4 v = p[j];
      s1 += v.x+v.y+v.z+v.w;
      s2 += v.x*v.x + v.y*v.y + v.z*v.z + v.w*v.w;
    }
  }
  #pragma unroll
  for (int m=1;m<64;m<<=1){ s1 += __shfl_xor(s1,m); s2 += __shfl_xor(s2,m); }
  __shared__ float red[16];
  __shared__ float mv[2];
  int wid = t>>6;
  if ((t&63)==0){ red[wid*2]=s1; red[wid*2+1]=s2; }
  __syncthreads();
  if (t==0){
    float a=0,c=0;
    #pragma unroll
    for (int w2=0;w2<8;++w2){ a+=red[w2*2]; c+=red[w2*2+1]; }
    float mean = a*(1.f/16384.f);
    float var  = c*(1.f/16384.f) - mean*mean;
    mv[0] = mean; mv[1] = rsqrtf(var + 1e-5f);
  }
  __syncthreads();
  float mean = mv[0], rstd = mv[1];
  float sc[16], bi[16];
  #pragma unroll
  for (int j=0;j<16;++j){ sc[j] = scale[g*16+j]*rstd; bi[j] = bias[g*16+j] - mean*scale[g*16+j]*rstd; }
  for (int s = t; s < SLEN; s += 512){
    const float* xp = base + (size_t)s*CDIM;   // L2-hot re-read
    short8 o0, o1;
    #pragma unroll
    for (int j=0;j<16;++j){
      float v = xp[j]*sc[j] + bi[j];
      if (j<8) o0[j] = (short)f2bf(v); else o1[j-8] = (short)f2bf(v);
    }
    short8* dst = (short8*)(obase + (size_t)s*CDIM);
    dst[0]=o0; dst[1]=o1;
  }
}

// ---------------- GEMM: C = A(MxK) * Bt(NxK)^T, bf16 in, fp32 acc ----------------
#define BM 128
#define BN 128
#define BK 64

template<int EPI, int NT>
__global__ __launch_bounds__(256, 3) void gemm_bf16(
    const u16* __restrict__ A, const u16* __restrict__ Bt,
    const float* __restrict__ bias, const float* __restrict__ resid,
    float* __restrict__ outF,
    u16* __restrict__ qb, u16* __restrict__ kb, u16* __restrict__ vtb)
{
  const int K = CDIM;
  int t = threadIdx.x;
  int l = t & 63, wid = t >> 6;
  int g = l >> 4, c = l & 15;
  int wr = wid >> 1, wc = wid & 1;
  int nwg = gridDim.x;
  int cpx = nwg >> 3;
  int orig = blockIdx.x;
  int swz = (orig & 7)*cpx + (orig >> 3);
  int m0 = (swz / NT) * BM, n0 = (swz % NT) * BN;

  __shared__ __attribute__((aligned(16))) u16 ls[16384];   // 32 KB
  char* lsAc = (char*)ls; char* lsBc = (char*)(ls + 8192);

  f32x4 acc[4][4];
  #pragma unroll
  for (int i=0;i<4;++i)
    #pragma unroll
    for(int j=0;j<4;++j) acc[i][j] = (f32x4)0.f;

  int lrow = l >> 3, slot = l & 7;
  int scol = ((slot ^ lrow) << 3);
  const int KT = K / BK;  // 8
  for (int kt=0; kt<KT; ++kt){
    __syncthreads();
    int kbo = kt*BK;
    #pragma unroll
    for (int q2=0; q2<4; ++q2){
      int row = wid*32 + q2*8 + lrow;
      gld16(A  + (size_t)(m0+row)*K + kbo + scol, ls        + (wid*4+q2)*512);
      gld16(Bt + (size_t)(n0+row)*K + kbo + scol, ls + 8192 + (wid*4+q2)*512);
    }
    asm volatile("s_waitcnt vmcnt(0)" ::: "memory");
    __syncthreads();
    #pragma unroll
    for (int kk=0; kk<2; ++kk){
      short8 af[4], bfr[4];
      #pragma unroll
      for (int i=0;i<4;++i){
        int rowA = wr*64 + i*16 + c;
        af[i]  = *(const short8*)(lsAc + rowA*128 + ((kk*4+g) ^ (rowA&7))*16);
        int rowB = wc*64 + i*16 + c;
        bfr[i] = *(const short8*)(lsBc + rowB*128 + ((kk*4+g) ^ (rowB&7))*16);
      }
      #pragma unroll
      for (int i=0;i<4;++i)
        #pragma unroll
        for (int j=0;j<4;++j)
          acc[i][j] = __builtin_amdgcn_mfma_f32_16x16x32_bf16(af[i], bfr[j], acc[i][j], 0,0,0);
    }
  }

  if (EPI == 0){
    int b = m0 >> 10, s0 = m0 & (SLEN-1);
    __syncthreads();
    u16* lsC = ls;
    #pragma unroll
    for (int i=0;i<4;++i){
      int rl0 = wr*64 + i*16 + g*4;
      #pragma unroll
      for (int j=0;j<4;++j){
        int cl = wc*64 + j*16 + c;
        int gcol = n0 + cl;
        int jj = gcol % 192;
        float sc_ = (jj < 64) ? Q_SCALE_L2E : 1.0f;
        float bv = bias[gcol];
        #pragma unroll
        for (int r=0;r<4;++r)
          lsC[(rl0+r)*128 + cl] = f2bf((acc[i][j][r] + bv)*sc_);
      }
    }
    __syncthreads();
    #pragma unroll
    for (int cc=0; cc<8; ++cc){
      int ch = cc*256 + t;
      int rl = ch >> 4, slot2 = ch & 15;
      int cl = slot2*8;
      int gcol = n0 + cl;
      int h = gcol / 192, jj = gcol % 192;
      int s = s0 + rl;
      u32x4 vv = *(const u32x4*)(lsC + rl*128 + cl);
      size_t rowb = ((size_t)(b*NHEADS+h))*SLEN + s;
      if (jj < 64)       __builtin_nontemporal_store(vv, (u32x4*)(qb + rowb*HDIM + jj));
      else if (jj < 128) __builtin_nontemporal_store(vv, (u32x4*)(kb + rowb*HDIM + (jj-64)));
    }
    int blk3 = (n0 >> 7) % 3;
    if (blk3 != 0){
      __syncthreads();
      u16* lsV = ls;            // [64][136] padded
      #pragma unroll
      for (int i=0;i<4;++i){
        int rl0 = wr*64 + i*16 + g*4;
        #pragma unroll
        for (int j=0;j<4;++j){
          int cl = wc*64 + j*16 + c;
          int jj = (n0 + cl) % 192;
          if (jj >= 128){
            #pragma unroll
            for (int r=0;r<4;++r)
              lsV[(jj-128)*136 + rl0 + r] = f2bf(acc[i][j][r] + bias[n0+cl]);
          }
        }
      }
      __syncthreads();
      int hv = (n0 + ((blk3==1)?0:64)) / 192;
      size_t vbase = ((size_t)(b*NHEADS+hv))*HDIM*SLEN;
      #pragma unroll
      for (int cc=0; cc<4; ++cc){
        int chunk = cc*256 + t;
        int d = chunk >> 4, so = (chunk & 15)*8;
        u32x4 vv = *(const u32x4*)(lsV + d*136 + so);
        __builtin_nontemporal_store(vv, (u32x4*)(vtb + vbase + (size_t)d*SLEN + s0 + so));
      }
    }
  } else {
    #pragma unroll
    for (int i=0;i<4;++i){
      int grow = m0 + wr*64 + i*16 + g*4;
      #pragma unroll
      for (int j=0;j<4;++j){
        int gcol = n0 + wc*64 + j*16 + c;
        float bv = bias[gcol];
        #pragma unroll
        for (int r=0;r<4;++r){
          size_t off = (size_t)(grow+r)*CDIM + gcol;
          float rv = __builtin_nontemporal_load(&resid[off]);
          __builtin_nontemporal_store(acc[i][j][r] + bv + rv, &outF[off]);
        }
      }
    }
  }
}

// ---------------- fused flash attention: swapped-QK^T 32x32, PAIR-MERGED kv loop ----
// exp2-domain logits; split PV accumulators; VECTOR lsum accumulator (reduced once).
#define PV_KS(PT, QOFF, V0, V1, KS, OA, OB) { \
    u32 A0 = pk2(PT[QOFF+0], PT[QOFF+1]); \
    u32 A1 = pk2(PT[QOFF+2], PT[QOFF+3]); \
    u32 B0 = pk2(PT[QOFF+4], PT[QOFF+5]); \
    u32 B1 = pk2(PT[QOFF+6], PT[QOFF+7]); \
    auto r0_ = __builtin_amdgcn_permlane32_swap((int)A0, (int)B0, false, false); \
    auto r1_ = __builtin_amdgcn_permlane32_swap((int)A1, (int)B1, false, false); \
    uint4 w; \
    w.x = (u32)r0_[0]; w.y = (u32)r1_[0]; w.z = (u32)r0_[1]; w.w = (u32)r1_[1]; \
    short8 fP; __builtin_memcpy(&fP, &w, 16); \
    OA = __builtin_amdgcn_mfma_f32_32x32x16_bf16(V0[KS], fP, OA, 0,0,0); \
    OB = __builtin_amdgcn_mfma_f32_32x32x16_bf16(V1[KS], fP, OB, 0,0,0); }

__global__ __launch_bounds__(256, 2) void attn_fused(const u16* __restrict__ qg,
  const u16* __restrict__ kg, const u16* __restrict__ vtg, u16* __restrict__ og)
{
  int bid = blockIdx.x;
  int nid = (bid & 7)*64 + (bid >> 3);   // XCD-contiguous bh
  int bh = nid >> 3, qi = nid & 7;
  int t = threadIdx.x, l = t & 63, wid = t >> 6;
  int q = l & 31, hi = l >> 5;
  int q0 = qi*128 + wid*32;

  __shared__ __attribute__((aligned(16))) u16 kl[4][4096];
  __shared__ __attribute__((aligned(16))) u16 vl[4][4096];

  const u16* qrow = qg + ((size_t)bh*SLEN + q0 + q)*HDIM + hi*8;
  short8 fQ[4];
  #pragma unroll
  for (int ds=0; ds<4; ++ds) fQ[ds] = *(const short8*)(qrow + ds*16);

  f32x16 o0a, o0b, o1a, o1b, ssum;
  #pragma unroll
  for (int r=0;r<16;++r){ o0a[r]=0.f; o0b[r]=0.f; o1a[r]=0.f; o1b[r]=0.f; ssum[r]=0.f; }
  float mr = -1e30f;

  const u16* kt_base = kg  + (size_t)bh*SLEN*HDIM;
  const u16* vt_base = vtg + (size_t)bh*HDIM*SLEN;
  int srow = l >> 3, sslot = l & 7;
  int scol8 = ((sslot ^ srow) << 3);

#define STAGE(BUF, KV) { \
    _Pragma("unroll") \
    for (int j=0;j<2;++j){ \
      int row = wid*16 + j*8 + srow; \
      int chunk = wid*2 + j; \
      gld16(kt_base + (size_t)((KV)*64 + row)*HDIM + scol8, &kl[BUF][chunk*512]); \
      gld16(vt_base + (size_t)row*SLEN + (KV)*64 + scol8,   &vl[BUF][chunk*512]); \
    } }

  STAGE(0, 0)
  STAGE(1, 1)
  STAGE(2, 2)
  STAGE(3, 3)

  int sl_q = q & 7;
  for (int p=0; p<8; ++p){
    if (p < 7) asm volatile("s_waitcnt vmcnt(8)" ::: "memory");
    else       asm volatile("s_waitcnt vmcnt(0)" ::: "memory");
    __syncthreads();
    int tA = 2*p, tB = 2*p+1;
    const u16* kA = &kl[tA&3][0]; const u16* kB = &kl[tB&3][0];
    const u16* vA = &vl[tA&3][0]; const u16* vB = &vl[tB&3][0];
    short8 fKA0[4], fKA1[4], fKB0[4], fKB1[4];
    #pragma unroll
    for (int ds=0; ds<4; ++ds){
      int sl = ((ds*2+hi) ^ sl_q) << 3;
      fKA0[ds] = *(const short8*)(kA + q*64 + sl);
      fKA1[ds] = *(const short8*)(kA + (q+32)*64 + sl);
      fKB0[ds] = *(const short8*)(kB + q*64 + sl);
      fKB1[ds] = *(const short8*)(kB + (q+32)*64 + sl);
    }
    f32x16 pA0, pA1, pB0, pB1;
    #pragma unroll
    for (int r=0;r<16;++r){ pA0[r]=0.f; pA1[r]=0.f; pB0[r]=0.f; pB1[r]=0.f; }
    __builtin_amdgcn_s_setprio(1);
    #pragma unroll
    for (int ds=0; ds<4; ++ds){
      pA0 = __builtin_amdgcn_mfma_f32_32x32x16_bf16(fKA0[ds], fQ[ds], pA0, 0,0,0);
      pB0 = __builtin_amdgcn_mfma_f32_32x32x16_bf16(fKB0[ds], fQ[ds], pB0, 0,0,0);
      pA1 = __builtin_amdgcn_mfma_f32_32x32x16_bf16(fKA1[ds], fQ[ds], pA1, 0,0,0);
      pB1 = __builtin_amdgcn_mfma_f32_32x32x16_bf16(fKB1[ds], fQ[ds], pB1, 0,0,0);
    }
    __builtin_amdgcn_s_setprio(0);
    short8 fVA0[4], fVA1[4], fVB0[4], fVB1[4];
    #pragma unroll
    for (int ks=0; ks<4; ++ks){
      int sl = ((ks*2+hi) ^ sl_q) << 3;
      fVA0[ks] = *(const short8*)(vA + q*64 + sl);
      fVA1[ks] = *(const short8*)(vA + (q+32)*64 + sl);
      fVB0[ks] = *(const short8*)(vB + q*64 + sl);
      fVB1[ks] = *(const short8*)(vB + (q+32)*64 + sl);
    }
    float a8[8];
    #pragma unroll
    for (int r=0;r<8;++r){
      float ma = fmaxf(fmaxf(pA0[r],pA0[r+8]), fmaxf(pA1[r],pA1[r+8]));
      float mb = fmaxf(fmaxf(pB0[r],pB0[r+8]), fmaxf(pB1[r],pB1[r+8]));
      a8[r] = fmaxf(ma, mb);
    }
    #pragma unroll
    for (int s=4;s>0;s>>=1)
      #pragma unroll
      for (int r=0;r<4;++r) if (r<s) a8[r] = fmaxf(a8[r], a8[r+s]);
    auto rm_ = __builtin_amdgcn_permlane32_swap(
        __builtin_bit_cast(int, a8[0]), __builtin_bit_cast(int, a8[0]), false, false);
    float tmax = fmaxf(a8[0], fmaxf(__builtin_bit_cast(float, rm_[0]),
                                    __builtin_bit_cast(float, rm_[1])));
    if (!__all(tmax <= mr + DEFER_THR)){
      float mn = fmaxf(mr, tmax);
      float alpha = exp2r(mr - mn);
      mr = mn;
      #pragma unroll
      for (int r=0;r<16;++r){
        ssum[r]*=alpha;
        o0a[r]*=alpha; o0b[r]*=alpha; o1a[r]*=alpha; o1b[r]*=alpha;
      }
    }
    #pragma unroll
    for (int r=0;r<16;++r){
      pA0[r] = exp2r(pA0[r]-mr); pA1[r] = exp2r(pA1[r]-mr);
      pB0[r] = exp2r(pB0[r]-mr); pB1[r] = exp2r(pB1[r]-mr);
    }
    // vector accumulation of the softmax denominator (no tree in-loop)
    #pragma unroll
    for (int r=0;r<16;++r)
      ssum[r] += (pA0[r]+pA1[r]) + (pB0[r]+pB1[r]);
    __builtin_amdgcn_s_setprio(1);
    PV_KS(pA0, 0, fVA0, fVA1, 0, o0a, o1a)
    PV_KS(pA0, 8, fVA0, fVA1, 1, o0a, o1a)
    PV_KS(pA1, 0, fVA0, fVA1, 2, o0b, o1b)
    PV_KS(pA1, 8, fVA0, fVA1, 3, o0b, o1b)
    PV_KS(pB0, 0, fVB0, fVB1, 0, o0a, o1a)
    PV_KS(pB0, 8, fVB0, fVB1, 1, o0a, o1a)
    PV_KS(pB1, 0, fVB0, fVB1, 2, o0b, o1b)
    PV_KS(pB1, 8, fVB0, fVB1, 3, o0b, o1b)
    __builtin_amdgcn_s_setprio(0);
    __syncthreads();
    if (p < 6){
      STAGE((2*p+4)&3, 2*p+4)
      STAGE((2*p+5)&3, 2*p+5)
    }
  }

  // epilogue: reduce ssum once, then write O^T
  float s8[8];
  #pragma unroll
  for (int r=0;r<8;++r) s8[r] = ssum[r] + ssum[r+8];
  #pragma unroll
  for (int s=4;s>0;s>>=1)
    #pragma unroll
    for (int r=0;r<4;++r) if (r<s) s8[r] += s8[r+s];
  auto rs_ = __builtin_amdgcn_permlane32_swap(
      __builtin_bit_cast(int, s8[0]), __builtin_bit_cast(int, s8[0]), false, false);
  float lsum = __builtin_bit_cast(float, rs_[0]) + __builtin_bit_cast(float, rs_[1]);
  float inv = 1.f / lsum;
  int b = bh >> 3, h = bh & 7;
  u16* obase = og + ((size_t)b*SLEN + q0 + q)*CDIM + h*HDIM;
  #pragma unroll
  for (int pr=0; pr<8; ++pr){
    int d = ((2*pr)&3) + 8*(pr>>1) + 4*hi;
    *(u32*)(obase + d)      = pk2((o0a[2*pr]+o0b[2*pr])*inv, (o0a[2*pr+1]+o0b[2*pr+1])*inv);
    *(u32*)(obase + 32 + d) = pk2((o1a[2*pr]+o1b[2*pr])*inv, (o1a[2*pr+1]+o1b[2*pr+1])*inv);
  }
}

extern "C" void kernel_launch(void* const* d_in, const int* in_sizes, int n_in,
                              void* d_out, int out_size, void* d_ws, size_t ws_size,
                              hipStream_t stream){
  const float* x      = (const float*)d_in[0];
  const float* nscale = (const float*)d_in[1];
  const float* nbias  = (const float*)d_in[2];
  const float* wqkv   = (const float*)d_in[3];
  const float* bqkv   = (const float*)d_in[4];
  const float* wout   = (const float*)d_in[5];
  const float* bout   = (const float*)d_in[6];
  float* out = (float*)d_out;

  char* ws = (char*)d_ws;
  size_t off = 0;
  auto alloc = [&](size_t bytes){ void* p = ws + off; off += (bytes + 255) & ~255ull; return p; };
  u16* wqkv_t = (u16*)alloc((size_t)NQKV*CDIM*2);
  u16* wout_t = (u16*)alloc((size_t)CDIM*CDIM*2);
  u16* xn     = (u16*)alloc((size_t)MROWS*CDIM*2);
  u16* qb     = (u16*)alloc((size_t)MROWS*CDIM*2);
  u16* kb     = (u16*)alloc((size_t)MROWS*CDIM*2);
  u16* vtb    = (u16*)alloc((size_t)MROWS*CDIM*2);
  u16* ob     = (u16*)alloc((size_t)MROWS*CDIM*2);

  pre_fused<<<dim3(NPREP + 256), dim3(512), 0, stream>>>(wqkv, wout, wqkv_t, wout_t,
                                                         x, nscale, nbias, xn);
  gemm_bf16<0,12><<<dim3(768), dim3(256), 0, stream>>>(xn, wqkv_t, bqkv, nullptr, nullptr, qb, kb, vtb);
  attn_fused<<<dim3(512), dim3(256), 0, stream>>>(qb, kb, vtb, ob);
  gemm_bf16<1,4><<<dim3(256), dim3(256), 0, stream>>>(ob, wout_t, bout, x, out, nullptr, nullptr, nullptr);
}

// Round 18
// 87.389 us; speedup vs baseline: 1.0831x; 1.0831x over previous
//
#include <hip/hip_runtime.h>
#include <stdint.h>

typedef __attribute__((ext_vector_type(8))) short short8;
typedef __attribute__((ext_vector_type(4))) float f32x4;
typedef __attribute__((ext_vector_type(16))) float f32x16;
typedef __attribute__((ext_vector_type(4))) unsigned int u32x4;
typedef unsigned short u16;
typedef unsigned int u32;

#define NBATCH 8
#define SLEN 1024
#define CDIM 512
#define NHEADS 8
#define HDIM 64
#define MROWS (NBATCH*SLEN)
#define NQKV (NHEADS*3*HDIM)   // 1536
// q-scale with folded log2e: QK_SCALE^2 * log2(e) = 0.125 * 1.4426950408889634
#define Q_SCALE_L2E 0.18033688011111793f
#define DEFER_THR 11.541560327111707f   // 8 * log2(e)
#define NPREP (8*(NQKV/64) + 8*(CDIM/64))   // 320 transpose blocks

__device__ inline u16 f2bf(float f){
  union{float f; uint32_t i;} v; v.f=f;
  uint32_t r = v.i + 0x7fffu + ((v.i>>16)&1u);
  return (u16)(r>>16);
}

__device__ inline u32 pk2(float a, float b){
  u32 r;
  asm("v_cvt_pk_bf16_f32 %0, %1, %2" : "=v"(r) : "v"(a), "v"(b));
  return r;
}

// raw 2^x (v_exp_f32)
__device__ inline float exp2r(float x){
  float r;
  asm("v_exp_f32 %0, %1" : "=v"(r) : "v"(x));
  return r;
}

__device__ __forceinline__ void gld16(const u16* g, u16* l){
  __builtin_amdgcn_global_load_lds(
    (const __attribute__((address_space(1))) void*)g,
    (__attribute__((address_space(3))) void*)l, 16, 0, 0);
}

// ---------------- fused pre-pass: weight transposes + groupnorm, ONE dispatch ----
// blocks [0, NPREP): LDS-tiled transpose fp32[K=512][N] -> bf16[N][512] (512 thr)
// blocks [NPREP, NPREP+256): groupnorm stats+normalize per (b,g)
__device__ __forceinline__ void prep_body(const float* __restrict__ w, u16* __restrict__ wt,
                                          int N, int blk, int t){
  int tk = blk / (N/64), tn = blk % (N/64);
  int k0 = tk*64, n0 = tn*64;
  __shared__ u16 lt[64][72];
  int row = t >> 3, slot = t & 7;          // 64 rows x 8 slots of 8 elems
  const float* src = w + (size_t)(k0+row)*N + n0 + slot*8;
  #pragma unroll
  for (int j=0;j<8;++j)
    lt[row][slot*8+j] = f2bf(src[j]);
  __syncthreads();
  u16 tmp[8];
  #pragma unroll
  for (int j=0;j<8;++j) tmp[j] = lt[slot*8+j][row];
  *(u32x4*)(wt + (size_t)(n0+row)*512 + k0 + slot*8) = *(u32x4*)tmp;
}

__global__ __launch_bounds__(512) void pre_fused(
    const float* __restrict__ wqkv, const float* __restrict__ wout,
    u16* __restrict__ wqkv_t, u16* __restrict__ wout_t,
    const float* __restrict__ x, const float* __restrict__ scale,
    const float* __restrict__ bias, u16* __restrict__ xn){
  int blk = blockIdx.x, t = threadIdx.x;
  if (blk < NPREP){
    if (blk < 8*(NQKV/64)) prep_body(wqkv, wqkv_t, NQKV, blk, t);
    else                   prep_body(wout, wout_t, CDIM, blk - 8*(NQKV/64), t);
    return;
  }
  int bid = blk - NPREP;           // b*32+g
  int b = bid >> 5, g = bid & 31;
  const float* base = x + (size_t)b*SLEN*CDIM + g*16;
  u16* obase = xn + (size_t)b*SLEN*CDIM + g*16;
  float s1=0.f, s2=0.f;
  for (int s = t; s < SLEN; s += 512){
    const float4* p = (const float4*)(base + (size_t)s*CDIM);
    #pragma unroll
    for (int j=0;j<4;++j){
      float4 v = p[j];
      s1 += v.x+v.y+v.z+v.w;
      s2 += v.x*v.x + v.y*v.y + v.z*v.z + v.w*v.w;
    }
  }
  #pragma unroll
  for (int m=1;m<64;m<<=1){ s1 += __shfl_xor(s1,m); s2 += __shfl_xor(s2,m); }
  __shared__ float red[16];
  __shared__ float mv[2];
  int wid = t>>6;
  if ((t&63)==0){ red[wid*2]=s1; red[wid*2+1]=s2; }
  __syncthreads();
  if (t==0){
    float a=0,c=0;
    #pragma unroll
    for (int w2=0;w2<8;++w2){ a+=red[w2*2]; c+=red[w2*2+1]; }
    float mean = a*(1.f/16384.f);
    float var  = c*(1.f/16384.f) - mean*mean;
    mv[0] = mean; mv[1] = rsqrtf(var + 1e-5f);
  }
  __syncthreads();
  float mean = mv[0], rstd = mv[1];
  float sc[16], bi[16];
  #pragma unroll
  for (int j=0;j<16;++j){ sc[j] = scale[g*16+j]*rstd; bi[j] = bias[g*16+j] - mean*scale[g*16+j]*rstd; }
  for (int s = t; s < SLEN; s += 512){
    const float* xp = base + (size_t)s*CDIM;   // L2-hot re-read
    short8 o0, o1;
    #pragma unroll
    for (int j=0;j<16;++j){
      float v = xp[j]*sc[j] + bi[j];
      if (j<8) o0[j] = (short)f2bf(v); else o1[j-8] = (short)f2bf(v);
    }
    short8* dst = (short8*)(obase + (size_t)s*CDIM);
    dst[0]=o0; dst[1]=o1;
  }
}

// ---------------- GEMM: C = A(MxK) * Bt(NxK)^T, bf16 in, fp32 acc ----------------
#define BM 128
#define BN 128
#define BK 64

template<int EPI, int NT>
__global__ __launch_bounds__(256, 3) void gemm_bf16(
    const u16* __restrict__ A, const u16* __restrict__ Bt,
    const float* __restrict__ bias, const float* __restrict__ resid,
    float* __restrict__ outF,
    u16* __restrict__ qb, u16* __restrict__ kb, u16* __restrict__ vtb)
{
  const int K = CDIM;
  int t = threadIdx.x;
  int l = t & 63, wid = t >> 6;
  int g = l >> 4, c = l & 15;
  int wr = wid >> 1, wc = wid & 1;
  int nwg = gridDim.x;
  int cpx = nwg >> 3;
  int orig = blockIdx.x;
  int swz = (orig & 7)*cpx + (orig >> 3);
  int m0 = (swz / NT) * BM, n0 = (swz % NT) * BN;

  __shared__ __attribute__((aligned(16))) u16 ls[16384];   // 32 KB
  char* lsAc = (char*)ls; char* lsBc = (char*)(ls + 8192);

  f32x4 acc[4][4];
  #pragma unroll
  for (int i=0;i<4;++i)
    #pragma unroll
    for(int j=0;j<4;++j) acc[i][j] = (f32x4)0.f;

  int lrow = l >> 3, slot = l & 7;
  int scol = ((slot ^ lrow) << 3);
  const int KT = K / BK;  // 8
  for (int kt=0; kt<KT; ++kt){
    __syncthreads();
    int kbo = kt*BK;
    #pragma unroll
    for (int q2=0; q2<4; ++q2){
      int row = wid*32 + q2*8 + lrow;
      gld16(A  + (size_t)(m0+row)*K + kbo + scol, ls        + (wid*4+q2)*512);
      gld16(Bt + (size_t)(n0+row)*K + kbo + scol, ls + 8192 + (wid*4+q2)*512);
    }
    asm volatile("s_waitcnt vmcnt(0)" ::: "memory");
    __syncthreads();
    #pragma unroll
    for (int kk=0; kk<2; ++kk){
      short8 af[4], bfr[4];
      #pragma unroll
      for (int i=0;i<4;++i){
        int rowA = wr*64 + i*16 + c;
        af[i]  = *(const short8*)(lsAc + rowA*128 + ((kk*4+g) ^ (rowA&7))*16);
        int rowB = wc*64 + i*16 + c;
        bfr[i] = *(const short8*)(lsBc + rowB*128 + ((kk*4+g) ^ (rowB&7))*16);
      }
      #pragma unroll
      for (int i=0;i<4;++i)
        #pragma unroll
        for (int j=0;j<4;++j)
          acc[i][j] = __builtin_amdgcn_mfma_f32_16x16x32_bf16(af[i], bfr[j], acc[i][j], 0,0,0);
    }
  }

  if (EPI == 0){
    int b = m0 >> 10, s0 = m0 & (SLEN-1);
    __syncthreads();
    u16* lsC = ls;
    #pragma unroll
    for (int i=0;i<4;++i){
      int rl0 = wr*64 + i*16 + g*4;
      #pragma unroll
      for (int j=0;j<4;++j){
        int cl = wc*64 + j*16 + c;
        int gcol = n0 + cl;
        int jj = gcol % 192;
        float sc_ = (jj < 64) ? Q_SCALE_L2E : 1.0f;
        float bv = bias[gcol];
        #pragma unroll
        for (int r=0;r<4;++r)
          lsC[(rl0+r)*128 + cl] = f2bf((acc[i][j][r] + bv)*sc_);
      }
    }
    __syncthreads();
    #pragma unroll
    for (int cc=0; cc<8; ++cc){
      int ch = cc*256 + t;
      int rl = ch >> 4, slot2 = ch & 15;
      int cl = slot2*8;
      int gcol = n0 + cl;
      int h = gcol / 192, jj = gcol % 192;
      int s = s0 + rl;
      u32x4 vv = *(const u32x4*)(lsC + rl*128 + cl);
      size_t rowb = ((size_t)(b*NHEADS+h))*SLEN + s;
      if (jj < 64)       __builtin_nontemporal_store(vv, (u32x4*)(qb + rowb*HDIM + jj));
      else if (jj < 128) __builtin_nontemporal_store(vv, (u32x4*)(kb + rowb*HDIM + (jj-64)));
    }
    int blk3 = (n0 >> 7) % 3;
    if (blk3 != 0){
      __syncthreads();
      u16* lsV = ls;            // [64][136] padded
      #pragma unroll
      for (int i=0;i<4;++i){
        int rl0 = wr*64 + i*16 + g*4;
        #pragma unroll
        for (int j=0;j<4;++j){
          int cl = wc*64 + j*16 + c;
          int jj = (n0 + cl) % 192;
          if (jj >= 128){
            #pragma unroll
            for (int r=0;r<4;++r)
              lsV[(jj-128)*136 + rl0 + r] = f2bf(acc[i][j][r] + bias[n0+cl]);
          }
        }
      }
      __syncthreads();
      int hv = (n0 + ((blk3==1)?0:64)) / 192;
      size_t vbase = ((size_t)(b*NHEADS+hv))*HDIM*SLEN;
      #pragma unroll
      for (int cc=0; cc<4; ++cc){
        int chunk = cc*256 + t;
        int d = chunk >> 4, so = (chunk & 15)*8;
        u32x4 vv = *(const u32x4*)(lsV + d*136 + so);
        __builtin_nontemporal_store(vv, (u32x4*)(vtb + vbase + (size_t)d*SLEN + s0 + so));
      }
    }
  } else {
    #pragma unroll
    for (int i=0;i<4;++i){
      int grow = m0 + wr*64 + i*16 + g*4;
      #pragma unroll
      for (int j=0;j<4;++j){
        int gcol = n0 + wc*64 + j*16 + c;
        float bv = bias[gcol];
        #pragma unroll
        for (int r=0;r<4;++r){
          size_t off = (size_t)(grow+r)*CDIM + gcol;
          float rv = __builtin_nontemporal_load(&resid[off]);
          __builtin_nontemporal_store(acc[i][j][r] + bv + rv, &outF[off]);
        }
      }
    }
  }
}

// ---------------- fused flash attention: swapped-QK^T 32x32, PAIR-MERGED kv loop ----
// exp2-domain logits (log2e folded into q); split PV accumulators (chain 8->4);
// scalar lsum with in-loop sum tree (r16-proven register budget).
#define PV_KS(PT, QOFF, V0, V1, KS, OA, OB) { \
    u32 A0 = pk2(PT[QOFF+0], PT[QOFF+1]); \
    u32 A1 = pk2(PT[QOFF+2], PT[QOFF+3]); \
    u32 B0 = pk2(PT[QOFF+4], PT[QOFF+5]); \
    u32 B1 = pk2(PT[QOFF+6], PT[QOFF+7]); \
    auto r0_ = __builtin_amdgcn_permlane32_swap((int)A0, (int)B0, false, false); \
    auto r1_ = __builtin_amdgcn_permlane32_swap((int)A1, (int)B1, false, false); \
    uint4 w; \
    w.x = (u32)r0_[0]; w.y = (u32)r1_[0]; w.z = (u32)r0_[1]; w.w = (u32)r1_[1]; \
    short8 fP; __builtin_memcpy(&fP, &w, 16); \
    OA = __builtin_amdgcn_mfma_f32_32x32x16_bf16(V0[KS], fP, OA, 0,0,0); \
    OB = __builtin_amdgcn_mfma_f32_32x32x16_bf16(V1[KS], fP, OB, 0,0,0); }

__global__ __launch_bounds__(256, 2) void attn_fused(const u16* __restrict__ qg,
  const u16* __restrict__ kg, const u16* __restrict__ vtg, u16* __restrict__ og)
{
  int bid = blockIdx.x;
  int nid = (bid & 7)*64 + (bid >> 3);   // XCD-contiguous bh
  int bh = nid >> 3, qi = nid & 7;
  int t = threadIdx.x, l = t & 63, wid = t >> 6;
  int q = l & 31, hi = l >> 5;
  int q0 = qi*128 + wid*32;

  __shared__ __attribute__((aligned(16))) u16 kl[4][4096];
  __shared__ __attribute__((aligned(16))) u16 vl[4][4096];

  const u16* qrow = qg + ((size_t)bh*SLEN + q0 + q)*HDIM + hi*8;
  short8 fQ[4];
  #pragma unroll
  for (int ds=0; ds<4; ++ds) fQ[ds] = *(const short8*)(qrow + ds*16);

  f32x16 o0a, o0b, o1a, o1b;
  #pragma unroll
  for (int r=0;r<16;++r){ o0a[r]=0.f; o0b[r]=0.f; o1a[r]=0.f; o1b[r]=0.f; }
  float mr = -1e30f, lsum = 0.f;

  const u16* kt_base = kg  + (size_t)bh*SLEN*HDIM;
  const u16* vt_base = vtg + (size_t)bh*HDIM*SLEN;
  int srow = l >> 3, sslot = l & 7;
  int scol8 = ((sslot ^ srow) << 3);

#define STAGE(BUF, KV) { \
    _Pragma("unroll") \
    for (int j=0;j<2;++j){ \
      int row = wid*16 + j*8 + srow; \
      int chunk = wid*2 + j; \
      gld16(kt_base + (size_t)((KV)*64 + row)*HDIM + scol8, &kl[BUF][chunk*512]); \
      gld16(vt_base + (size_t)row*SLEN + (KV)*64 + scol8,   &vl[BUF][chunk*512]); \
    } }

  STAGE(0, 0)
  STAGE(1, 1)
  STAGE(2, 2)
  STAGE(3, 3)

  int sl_q = q & 7;
  for (int p=0; p<8; ++p){
    if (p < 7) asm volatile("s_waitcnt vmcnt(8)" ::: "memory");
    else       asm volatile("s_waitcnt vmcnt(0)" ::: "memory");
    __syncthreads();
    int tA = 2*p, tB = 2*p+1;
    const u16* kA = &kl[tA&3][0]; const u16* kB = &kl[tB&3][0];
    const u16* vA = &vl[tA&3][0]; const u16* vB = &vl[tB&3][0];
    short8 fKA0[4], fKA1[4], fKB0[4], fKB1[4];
    #pragma unroll
    for (int ds=0; ds<4; ++ds){
      int sl = ((ds*2+hi) ^ sl_q) << 3;
      fKA0[ds] = *(const short8*)(kA + q*64 + sl);
      fKA1[ds] = *(const short8*)(kA + (q+32)*64 + sl);
      fKB0[ds] = *(const short8*)(kB + q*64 + sl);
      fKB1[ds] = *(const short8*)(kB + (q+32)*64 + sl);
    }
    f32x16 pA0, pA1, pB0, pB1;
    #pragma unroll
    for (int r=0;r<16;++r){ pA0[r]=0.f; pA1[r]=0.f; pB0[r]=0.f; pB1[r]=0.f; }
    __builtin_amdgcn_s_setprio(1);
    #pragma unroll
    for (int ds=0; ds<4; ++ds){
      pA0 = __builtin_amdgcn_mfma_f32_32x32x16_bf16(fKA0[ds], fQ[ds], pA0, 0,0,0);
      pB0 = __builtin_amdgcn_mfma_f32_32x32x16_bf16(fKB0[ds], fQ[ds], pB0, 0,0,0);
      pA1 = __builtin_amdgcn_mfma_f32_32x32x16_bf16(fKA1[ds], fQ[ds], pA1, 0,0,0);
      pB1 = __builtin_amdgcn_mfma_f32_32x32x16_bf16(fKB1[ds], fQ[ds], pB1, 0,0,0);
    }
    __builtin_amdgcn_s_setprio(0);
    short8 fVA0[4], fVA1[4], fVB0[4], fVB1[4];
    #pragma unroll
    for (int ks=0; ks<4; ++ks){
      int sl = ((ks*2+hi) ^ sl_q) << 3;
      fVA0[ks] = *(const short8*)(vA + q*64 + sl);
      fVA1[ks] = *(const short8*)(vA + (q+32)*64 + sl);
      fVB0[ks] = *(const short8*)(vB + q*64 + sl);
      fVB1[ks] = *(const short8*)(vB + (q+32)*64 + sl);
    }
    float a8[8];
    #pragma unroll
    for (int r=0;r<8;++r){
      float ma = fmaxf(fmaxf(pA0[r],pA0[r+8]), fmaxf(pA1[r],pA1[r+8]));
      float mb = fmaxf(fmaxf(pB0[r],pB0[r+8]), fmaxf(pB1[r],pB1[r+8]));
      a8[r] = fmaxf(ma, mb);
    }
    #pragma unroll
    for (int s=4;s>0;s>>=1)
      #pragma unroll
      for (int r=0;r<4;++r) if (r<s) a8[r] = fmaxf(a8[r], a8[r+s]);
    auto rm_ = __builtin_amdgcn_permlane32_swap(
        __builtin_bit_cast(int, a8[0]), __builtin_bit_cast(int, a8[0]), false, false);
    float tmax = fmaxf(a8[0], fmaxf(__builtin_bit_cast(float, rm_[0]),
                                    __builtin_bit_cast(float, rm_[1])));
    if (!__all(tmax <= mr + DEFER_THR)){
      float mn = fmaxf(mr, tmax);
      float alpha = exp2r(mr - mn);
      mr = mn;
      lsum *= alpha;
      #pragma unroll
      for (int r=0;r<16;++r){ o0a[r]*=alpha; o0b[r]*=alpha; o1a[r]*=alpha; o1b[r]*=alpha; }
    }
    #pragma unroll
    for (int r=0;r<16;++r){
      pA0[r] = exp2r(pA0[r]-mr); pA1[r] = exp2r(pA1[r]-mr);
      pB0[r] = exp2r(pB0[r]-mr); pB1[r] = exp2r(pB1[r]-mr);
    }
    float s8[8];
    #pragma unroll
    for (int r=0;r<8;++r)
      s8[r] = ((pA0[r]+pA0[r+8]) + (pA1[r]+pA1[r+8]))
            + ((pB0[r]+pB0[r+8]) + (pB1[r]+pB1[r+8]));
    #pragma unroll
    for (int s=4;s>0;s>>=1)
      #pragma unroll
      for (int r=0;r<4;++r) if (r<s) s8[r] += s8[r+s];
    auto rs_ = __builtin_amdgcn_permlane32_swap(
        __builtin_bit_cast(int, s8[0]), __builtin_bit_cast(int, s8[0]), false, false);
    lsum += __builtin_bit_cast(float, rs_[0]) + __builtin_bit_cast(float, rs_[1]);
    __builtin_amdgcn_s_setprio(1);
    PV_KS(pA0, 0, fVA0, fVA1, 0, o0a, o1a)
    PV_KS(pA0, 8, fVA0, fVA1, 1, o0a, o1a)
    PV_KS(pA1, 0, fVA0, fVA1, 2, o0b, o1b)
    PV_KS(pA1, 8, fVA0, fVA1, 3, o0b, o1b)
    PV_KS(pB0, 0, fVB0, fVB1, 0, o0a, o1a)
    PV_KS(pB0, 8, fVB0, fVB1, 1, o0a, o1a)
    PV_KS(pB1, 0, fVB0, fVB1, 2, o0b, o1b)
    PV_KS(pB1, 8, fVB0, fVB1, 3, o0b, o1b)
    __builtin_amdgcn_s_setprio(0);
    __syncthreads();
    if (p < 6){
      STAGE((2*p+4)&3, 2*p+4)
      STAGE((2*p+5)&3, 2*p+5)
    }
  }

  float inv = 1.f / lsum;
  int b = bh >> 3, h = bh & 7;
  u16* obase = og + ((size_t)b*SLEN + q0 + q)*CDIM + h*HDIM;
  #pragma unroll
  for (int pr=0; pr<8; ++pr){
    int d = ((2*pr)&3) + 8*(pr>>1) + 4*hi;
    *(u32*)(obase + d)      = pk2((o0a[2*pr]+o0b[2*pr])*inv, (o0a[2*pr+1]+o0b[2*pr+1])*inv);
    *(u32*)(obase + 32 + d) = pk2((o1a[2*pr]+o1b[2*pr])*inv, (o1a[2*pr+1]+o1b[2*pr+1])*inv);
  }
}

extern "C" void kernel_launch(void* const* d_in, const int* in_sizes, int n_in,
                              void* d_out, int out_size, void* d_ws, size_t ws_size,
                              hipStream_t stream){
  const float* x      = (const float*)d_in[0];
  const float* nscale = (const float*)d_in[1];
  const float* nbias  = (const float*)d_in[2];
  const float* wqkv   = (const float*)d_in[3];
  const float* bqkv   = (const float*)d_in[4];
  const float* wout   = (const float*)d_in[5];
  const float* bout   = (const float*)d_in[6];
  float* out = (float*)d_out;

  char* ws = (char*)d_ws;
  size_t off = 0;
  auto alloc = [&](size_t bytes){ void* p = ws + off; off += (bytes + 255) & ~255ull; return p; };
  u16* wqkv_t = (u16*)alloc((size_t)NQKV*CDIM*2);
  u16* wout_t = (u16*)alloc((size_t)CDIM*CDIM*2);
  u16* xn     = (u16*)alloc((size_t)MROWS*CDIM*2);
  u16* qb     = (u16*)alloc((size_t)MROWS*CDIM*2);
  u16* kb     = (u16*)alloc((size_t)MROWS*CDIM*2);
  u16* vtb    = (u16*)alloc((size_t)MROWS*CDIM*2);
  u16* ob     = (u16*)alloc((size_t)MROWS*CDIM*2);

  pre_fused<<<dim3(NPREP + 256), dim3(512), 0, stream>>>(wqkv, wout, wqkv_t, wout_t,
                                                         x, nscale, nbias, xn);
  gemm_bf16<0,12><<<dim3(768), dim3(256), 0, stream>>>(xn, wqkv_t, bqkv, nullptr, nullptr, qb, kb, vtb);
  attn_fused<<<dim3(512), dim3(256), 0, stream>>>(qb, kb, vtb, ob);
  gemm_bf16<1,4><<<dim3(256), dim3(256), 0, stream>>>(ob, wout_t, bout, x, out, nullptr, nullptr, nullptr);
}